// Round 9
// baseline (1116.273 us; speedup 1.0000x reference)
//
#include <hip/hip_runtime.h>
#include <hip/hip_bf16.h>
#include <math.h>

#define N_NODES   100000
#define N_CH      9
#define N_EDG     500000
#define NEG_SLOPE 0.2f
#define NBINS     N_NODES
#define NSLOT     10           // structure slots (batch2 = 10 graphs)
#define PACK_STRIDE 500016     // u32 per graph slot (+16 pad for 8-wide tail reads)

// bucket sort geometry (r4-verified)
#define CHUNK  4096            // edges per block in histA/scatterA
#define NBLK   123             // ceil(500000/4096)
#define NBUCK  391             // buckets of 256 nodes: dst>>8
#define MLEN   (NBUCK * NBLK)  // 48093 matrix entries per graph
#define NBA1   188             // ceil(MLEN/256) scan blocks
#define BCAP   4096            // LDS capacity per bucket (mean 1280, sigma~36)

// degree-sort geometry (r9)
#define PCHUNK 4096            // nodes per block in histP/scatterP
#define NPBLK  25              // ceil(100000/4096)
#define NCLS   16              // degree classes: min(ceil(deg/4),15)
#define PMLEN  (NCLS * NPBLK)  // 400 matrix entries per graph

// ---------------- utility ----------------

__device__ __forceinline__ float bf2f(unsigned short h) {
  return __uint_as_float(((unsigned)h) << 16);
}
// bf16 pair unpack straight from a u32 (lo = elem 2k, hi = elem 2k+1)
__device__ __forceinline__ float bflo(unsigned u) { return __uint_as_float(u << 16); }
__device__ __forceinline__ float bfhi(unsigned u) { return __uint_as_float(u & 0xffff0000u); }
__device__ __forceinline__ unsigned short f2bf(float f) {
  unsigned u = __float_as_uint(f);
  u += 0x7FFFu + ((u >> 16) & 1u);
  return (unsigned short)(u >> 16);
}
__device__ __forceinline__ float lrelu(float x) { return x > 0.f ? x : NEG_SLOPE * x; }
__device__ __forceinline__ int clampi(int x) {
  return x < 0 ? 0 : (x >= N_NODES ? N_NODES - 1 : x);
}

// ---------------- diagnostic: fill output with a constant (f32) ------------
__global__ __launch_bounds__(256) void write_const(float* __restrict__ out, float val) {
  int idx = blockIdx.x * 256 + threadIdx.x;
  out[idx] = val;
}

// ---------------- GEMM + fused attention dots ------------------------------
// H[M,64](bf16) = A[M,64] @ W[64,64](f32); also sS = H.a_src, sD = H.a_dst
// computed from the f32 accumulators (register-resident) via padded-LDS
// reduction.  256 thr, 128 rows/block, 8x4 thread tile.
#define GEMM_BODY(LOAD_A)                                                     \
  __shared__ float Ws[64 * 64];                                               \
  __shared__ float Xs[64 * 132];                                              \
  __shared__ float redS[128 * 17];   /* [row][cg] stride 17: 2-way conflicts */\
  __shared__ float redD[128 * 17];                                            \
  const int tx = threadIdx.x;                                                 \
  const int r0 = blockIdx.x * 128;                                            \
  _Pragma("unroll")                                                           \
  for (int i = 0; i < 16; ++i) Ws[tx + 256 * i] = W[tx + 256 * i];            \
  _Pragma("unroll")                                                           \
  for (int it = 0; it < 8; ++it) {                                            \
    int f = tx + 256 * it;                                                    \
    int r = f >> 4;                                                           \
    int k0 = (f & 15) << 2;                                                   \
    float4 v = make_float4(0.f, 0.f, 0.f, 0.f);                               \
    if (r0 + r < M) { LOAD_A }                                                \
    Xs[(k0 + 0) * 132 + r] = v.x;                                             \
    Xs[(k0 + 1) * 132 + r] = v.y;                                             \
    Xs[(k0 + 2) * 132 + r] = v.z;                                             \
    Xs[(k0 + 3) * 132 + r] = v.w;                                             \
  }                                                                           \
  __syncthreads();                                                            \
  const int cg = tx & 15, rg = tx >> 4;                                       \
  float acc[8][4];                                                            \
  _Pragma("unroll")                                                           \
  for (int i = 0; i < 8; ++i)                                                 \
    _Pragma("unroll")                                                         \
    for (int j = 0; j < 4; ++j) acc[i][j] = 0.f;                              \
  _Pragma("unroll 4")                                                         \
  for (int k = 0; k < 64; ++k) {                                              \
    float4 w4 = *(const float4*)(Ws + k * 64 + cg * 4);                       \
    float4 x0 = *(const float4*)(Xs + k * 132 + rg * 8);                      \
    float4 x1 = *(const float4*)(Xs + k * 132 + rg * 8 + 4);                  \
    float xr[8] = {x0.x, x0.y, x0.z, x0.w, x1.x, x1.y, x1.z, x1.w};           \
    float wr[4] = {w4.x, w4.y, w4.z, w4.w};                                   \
    _Pragma("unroll")                                                         \
    for (int i = 0; i < 8; ++i)                                               \
      _Pragma("unroll")                                                       \
      for (int j = 0; j < 4; ++j) acc[i][j] += xr[i] * wr[j];                 \
  }                                                                           \
  float4 s4 = *(const float4*)(a_src + cg * 4);                               \
  float4 d4 = *(const float4*)(a_dst + cg * 4);                               \
  _Pragma("unroll")                                                           \
  for (int i = 0; i < 8; ++i) {                                               \
    int row = rg * 8 + i;                                                     \
    redS[row * 17 + cg] =                                                     \
        acc[i][0] * s4.x + acc[i][1] * s4.y + acc[i][2] * s4.z + acc[i][3] * s4.w; \
    redD[row * 17 + cg] =                                                     \
        acc[i][0] * d4.x + acc[i][1] * d4.y + acc[i][2] * d4.z + acc[i][3] * d4.w; \
    int r = r0 + row;                                                         \
    if (r < M) {                                                              \
      ushort4 o;                                                              \
      o.x = f2bf(acc[i][0]); o.y = f2bf(acc[i][1]);                           \
      o.z = f2bf(acc[i][2]); o.w = f2bf(acc[i][3]);                           \
      *(ushort4*)(Hout + (size_t)r * 64 + cg * 4) = o;                        \
    }                                                                         \
  }                                                                           \
  __syncthreads();                                                            \
  if (tx < 128) {                                                             \
    float s = 0.f;                                                            \
    _Pragma("unroll")                                                         \
    for (int c2 = 0; c2 < 16; ++c2) s += redS[tx * 17 + c2];                  \
    if (r0 + tx < M) sS[r0 + tx] = s;                                         \
  } else {                                                                    \
    int row = tx - 128;                                                       \
    float s = 0.f;                                                            \
    _Pragma("unroll")                                                         \
    for (int c2 = 0; c2 < 16; ++c2) s += redD[row * 17 + c2];                 \
    if (r0 + row < M) sD[r0 + row] = s;                                       \
  }

__global__ __launch_bounds__(256) void gemm64_f32(const float* __restrict__ A,
                                                  const float* __restrict__ W,
                                                  const float* __restrict__ a_src,
                                                  const float* __restrict__ a_dst,
                                                  unsigned short* __restrict__ Hout,
                                                  float* __restrict__ sS,
                                                  float* __restrict__ sD, int M) {
  GEMM_BODY(v = *(const float4*)(A + (size_t)(r0 + r) * 64 + k0);)
}

__global__ __launch_bounds__(256) void gemm64_bf(const unsigned short* __restrict__ A,
                                                 const float* __restrict__ W,
                                                 const float* __restrict__ a_src,
                                                 const float* __restrict__ a_dst,
                                                 unsigned short* __restrict__ Hout,
                                                 float* __restrict__ sS,
                                                 float* __restrict__ sD, int M) {
  GEMM_BODY(ushort4 h = *(const ushort4*)(A + (size_t)(r0 + r) * 64 + k0);
            v.x = bf2f(h.x); v.y = bf2f(h.y); v.z = bf2f(h.z); v.w = bf2f(h.w);)
}

// ---------------- batched CSR build: atomic-free two-level bucket sort -----
// (r4-verified structure) + r9 degree-sorted node permutation.

__global__ __launch_bounds__(256) void histA(const int* __restrict__ EI, int base,
                                             int* __restrict__ histM) {
  const int g = blockIdx.y;
  const int* dst = EI + ((size_t)(base + g) * 2 + 1) * N_EDG;
  __shared__ int h[NBUCK];
  for (int i = threadIdx.x; i < NBUCK; i += 256) h[i] = 0;
  __syncthreads();
  const int e0 = blockIdx.x * CHUNK;
#pragma unroll
  for (int k = 0; k < CHUNK; k += 256) {
    int i = e0 + k + threadIdx.x;
    if (i < N_EDG) atomicAdd(&h[clampi(dst[i]) >> 8], 1);
  }
  __syncthreads();
  for (int i = threadIdx.x; i < NBUCK; i += 256)
    histM[(size_t)g * MLEN + i * NBLK + blockIdx.x] = h[i];
}

__global__ __launch_bounds__(256) void scanA1(int* __restrict__ data,
                                              int* __restrict__ bsum) {
  const int g = blockIdx.y;
  __shared__ int sh[256];
  int i = blockIdx.x * 256 + threadIdx.x;
  int x = (i < MLEN) ? data[(size_t)g * MLEN + i] : 0;
  sh[threadIdx.x] = x;
  __syncthreads();
  for (int off = 1; off < 256; off <<= 1) {
    int t = (threadIdx.x >= off) ? sh[threadIdx.x - off] : 0;
    __syncthreads();
    sh[threadIdx.x] += t;
    __syncthreads();
  }
  if (i < MLEN) data[(size_t)g * MLEN + i] = sh[threadIdx.x] - x;  // exclusive
  if (threadIdx.x == 255) bsum[g * 512 + blockIdx.x] = sh[255];
}

__global__ __launch_bounds__(512) void scanA2(int* __restrict__ bsum) {
  const int g = blockIdx.x;
  __shared__ int sh[512];
  int x = (threadIdx.x < NBA1) ? bsum[g * 512 + threadIdx.x] : 0;
  sh[threadIdx.x] = x;
  __syncthreads();
  for (int off = 1; off < 512; off <<= 1) {
    int t = (threadIdx.x >= off) ? sh[threadIdx.x - off] : 0;
    __syncthreads();
    sh[threadIdx.x] += t;
    __syncthreads();
  }
  if (threadIdx.x < NBA1) bsum[g * 512 + threadIdx.x] = sh[threadIdx.x] - x;  // exclusive
}

__global__ void scanA3(int* __restrict__ data, const int* __restrict__ bsum) {
  const int g = blockIdx.y;
  int i = blockIdx.x * 256 + threadIdx.x;
  if (i < MLEN) data[(size_t)g * MLEN + i] += bsum[g * 512 + blockIdx.x];
}

// block-local counting sort by coarse bucket + coalesced sequential writeout.
__global__ __launch_bounds__(256) void scatterA(const int* __restrict__ EI, int base,
                                                const int* __restrict__ histM,
                                                unsigned* __restrict__ pack) {
  const int g = blockIdx.y;
  const int* srcp = EI + ((size_t)(base + g) * 2 + 0) * N_EDG;
  const int* dstp = EI + ((size_t)(base + g) * 2 + 1) * N_EDG;
  __shared__ unsigned ed[CHUNK];          // 16 KB: bucket-grouped entries
  __shared__ unsigned short bkt[CHUNK];   // 8 KB: bucket id per slot
  __shared__ int lcnt[NBUCK];
  __shared__ int ebase[NBUCK];
  __shared__ int gbase[NBUCK];
  __shared__ int sc[512];
  const int t = threadIdx.x;
  const int e0 = blockIdx.x * CHUNK;
  const int nE = (N_EDG - e0 < CHUNK) ? (N_EDG - e0) : CHUNK;

  for (int i = t; i < NBUCK; i += 256) {
    lcnt[i] = 0;
    gbase[i] = histM[(size_t)g * MLEN + i * NBLK + blockIdx.x];
  }
  __syncthreads();
  // pass 1: local histogram (reads dst; stays hot in L1/L2 for pass 2)
  for (int k = t; k < nE; k += 256)
    atomicAdd(&lcnt[clampi(dstp[e0 + k]) >> 8], 1);
  __syncthreads();
  // block-wide inclusive scan of 512-padded lcnt (each thread owns 2 slots)
  int v0 = (t < NBUCK) ? lcnt[t] : 0;
  int v1 = (t + 256 < NBUCK) ? lcnt[t + 256] : 0;
  sc[t] = v0; sc[t + 256] = v1;
  __syncthreads();
  for (int off = 1; off < 512; off <<= 1) {
    int a0 = (t >= off) ? sc[t - off] : 0;
    int a1 = (t + 256 >= off) ? sc[t + 256 - off] : 0;
    __syncthreads();
    sc[t] += a0; sc[t + 256] += a1;
    __syncthreads();
  }
  if (t < NBUCK)       { ebase[t] = sc[t] - v0;             lcnt[t] = 0; }
  if (t + 256 < NBUCK) { ebase[t + 256] = sc[t + 256] - v1; lcnt[t + 256] = 0; }
  __syncthreads();
  // pass 2: scatter into LDS, bucket-grouped (rank via LDS atomics)
  for (int k = t; k < nE; k += 256) {
    int d = clampi(dstp[e0 + k]);
    int s = clampi(srcp[e0 + k]);
    int b = d >> 8;
    int slot = ebase[b] + atomicAdd(&lcnt[b], 1);
    ed[slot] = ((unsigned)s << 8) | (unsigned)(d & 255);
    bkt[slot] = (unsigned short)b;
  }
  __syncthreads();
  // pass 3: sequential write-out -> bucket-runs leave as consecutive lanes
  unsigned* pk = pack + (size_t)g * PACK_STRIDE;
  for (int i = t; i < nE; i += 256) {
    int b = bkt[i];
    pk[gbase[b] + (i - ebase[b])] = ed[i];
  }
}

__global__ __launch_bounds__(256) void sortB(const int* __restrict__ histM,
                                             unsigned* __restrict__ pack,
                                             int* __restrict__ rp) {
  const int g = blockIdx.y;
  const int b = blockIdx.x;   // bucket 0..390
  __shared__ unsigned ed[BCAP];
  __shared__ unsigned ed2[BCAP];
  __shared__ int cnt[256];
  __shared__ int sh[256];
  const int t = threadIdx.x;
  const int beg = histM[(size_t)g * MLEN + b * NBLK];
  const int end = (b + 1 < NBUCK) ? histM[(size_t)g * MLEN + (b + 1) * NBLK] : N_EDG;
  int m = end - beg;
  if (m > BCAP) m = BCAP;   // defensive: statistically impossible (78 sigma)
  unsigned* pk = pack + (size_t)g * PACK_STRIDE;

  cnt[t] = 0;
  __syncthreads();
  for (int i = t; i < m; i += 256) {
    unsigned w = pk[beg + i];
    ed[i] = w;
    atomicAdd(&cnt[w & 255u], 1);
  }
  __syncthreads();
  // block-wide Hillis-Steele inclusive scan of cnt -> sh
  int x = cnt[t];
  sh[t] = x;
  __syncthreads();
  for (int off = 1; off < 256; off <<= 1) {
    int tt = (t >= off) ? sh[t - off] : 0;
    __syncthreads();
    sh[t] += tt;
    __syncthreads();
  }
  // rp end-offsets for this bucket's nodes (global edge indexing)
  int n = b * 256 + t;
  if (n < N_NODES) rp[(size_t)g * NBINS + n] = beg + sh[t];
  // cursor = exclusive base
  cnt[t] = sh[t] - x;
  __syncthreads();
  // counting-sort scatter within LDS (order within a node is irrelevant)
  for (int i = t; i < m; i += 256) {
    unsigned w = ed[i];
    int pos = atomicAdd(&cnt[w & 255u], 1);
    ed2[pos] = w >> 8;                    // keep src only
  }
  __syncthreads();
  // in-place, fully coalesced write-back of dst-sorted src list
  for (int i = t; i < m; i += 256) pk[beg + i] = ed2[i];
}

// ---------------- degree-sorted node permutation (r9) ----------------------
// Nodes sorted by degree class min(ceil(deg/4),15) so each aggregate wave's
// four 16-lane groups get near-equal iteration counts (kills the ~37%
// divergence idle from E[max of 4 Poisson degrees]).  Same atomic-free
// hist/scan/staged-scatter pattern as the edge sort.  Input-static.

__global__ __launch_bounds__(256) void histP(const int* __restrict__ rp,
                                             int* __restrict__ histPM) {
  const int g = blockIdx.y;
  __shared__ int h[NCLS];
  if (threadIdx.x < NCLS) h[threadIdx.x] = 0;
  __syncthreads();
  const int n0 = blockIdx.x * PCHUNK;
  const int* rpg = rp + (size_t)g * NBINS;
  for (int k = threadIdx.x; k < PCHUNK; k += 256) {
    int n = n0 + k;
    if (n < N_NODES) {
      int deg = rpg[n] - (n ? rpg[n - 1] : 0);
      int cls = (deg + 3) >> 2; if (cls > 15) cls = 15;
      atomicAdd(&h[cls], 1);
    }
  }
  __syncthreads();
  if (threadIdx.x < NCLS)
    histPM[(size_t)g * PMLEN + threadIdx.x * NPBLK + blockIdx.x] = h[threadIdx.x];
}

__global__ __launch_bounds__(512) void scanP(int* __restrict__ histPM) {
  const int g = blockIdx.x;
  __shared__ int sh[512];
  int i = threadIdx.x;
  int x = (i < PMLEN) ? histPM[(size_t)g * PMLEN + i] : 0;
  sh[i] = x;
  __syncthreads();
  for (int off = 1; off < 512; off <<= 1) {
    int t = (i >= off) ? sh[i - off] : 0;
    __syncthreads();
    sh[i] += t;
    __syncthreads();
  }
  if (i < PMLEN) histPM[(size_t)g * PMLEN + i] = sh[i] - x;  // exclusive
}

__global__ __launch_bounds__(256) void scatterP(const int* __restrict__ rp,
                                                const int* __restrict__ histPM,
                                                int* __restrict__ perm) {
  const int g = blockIdx.y;
  __shared__ int ed[PCHUNK];              // 16 KB: class-grouped node ids
  __shared__ unsigned char bkt[PCHUNK];   // 4 KB
  __shared__ int lcnt[NCLS], ebase[NCLS], gbase[NCLS], sc[NCLS];
  const int t = threadIdx.x;
  const int n0 = blockIdx.x * PCHUNK;
  const int nN = (N_NODES - n0 < PCHUNK) ? (N_NODES - n0) : PCHUNK;
  const int* rpg = rp + (size_t)g * NBINS;
  if (t < NCLS) {
    lcnt[t] = 0;
    gbase[t] = histPM[(size_t)g * PMLEN + t * NPBLK + blockIdx.x];
  }
  __syncthreads();
  for (int k = t; k < nN; k += 256) {
    int n = n0 + k;
    int deg = rpg[n] - (n ? rpg[n - 1] : 0);
    int cls = (deg + 3) >> 2; if (cls > 15) cls = 15;
    atomicAdd(&lcnt[cls], 1);
  }
  __syncthreads();
  if (t == 0) {
    int run = 0;
    for (int c = 0; c < NCLS; ++c) { sc[c] = run; run += lcnt[c]; }
  }
  __syncthreads();
  if (t < NCLS) { ebase[t] = sc[t]; lcnt[t] = 0; }
  __syncthreads();
  for (int k = t; k < nN; k += 256) {
    int n = n0 + k;
    int deg = rpg[n] - (n ? rpg[n - 1] : 0);
    int cls = (deg + 3) >> 2; if (cls > 15) cls = 15;
    int slot = ebase[cls] + atomicAdd(&lcnt[cls], 1);
    ed[slot] = n;
    bkt[slot] = (unsigned char)cls;
  }
  __syncthreads();
  int* pm = perm + (size_t)g * NBINS;
  for (int i = t; i < nN; i += 256) {
    int c = bkt[i];
    pm[gbase[c] + (i - ebase[c])] = ed[i];
  }
}

// ---------------- per-node GAT aggregation (16 lanes per node) -------------
// Lane f = tx&15 permanently owns features 4f..4f+3 (no reduction shuffles).
// Node assignment via degree-sorted perm: groups in a wave have near-equal
// degree -> minimal lockstep idle.  4 edges per iteration, software-
// pipelined one iteration ahead (r8-verified).  den is lane-redundant.
// mode 0: X1=bf16(relu(v)); mode 1: online channel combine (O,Mn,Sn).
__global__ __launch_bounds__(256) void aggregate(const unsigned short* __restrict__ H,
                                                 const float* __restrict__ sS,
                                                 const float* __restrict__ sD,
                                                 const int* __restrict__ rp,  // end offsets
                                                 const int* __restrict__ perm,
                                                 const unsigned* __restrict__ pack,
                                                 const float* __restrict__ bias,
                                                 unsigned short* __restrict__ X1out,
                                                 const float* __restrict__ att_c,
                                                 float* __restrict__ O,
                                                 float* __restrict__ Mn,
                                                 float* __restrict__ Sn,
                                                 float* __restrict__ outF,
                                                 int mode, int first, int last) {
  const int n = perm[blockIdx.x * 16 + (threadIdx.x >> 4)];
  const int f = threadIdx.x & 15;       // feature quad: feats 4f..4f+3
  const int beg = (n == 0) ? 0 : rp[n - 1];
  const int end = rp[n];
  const float sDn = sD[n];
  const float wself = __expf(lrelu(sS[n] + sDn));

  // self loop
  uint2 hs = *(const uint2*)(H + ((size_t)n << 6) + (f << 2));
  float a0 = wself * bflo(hs.x);
  float a1 = wself * bfhi(hs.x);
  float a2 = wself * bflo(hs.y);
  float a3 = wself * bfhi(hs.y);
  float den = wself;

  // pipeline registers for the current iteration
  uint2 h[4];
  float ss[4];
  int vm[4];
  int j = beg;
  if (j < end) {
#pragma unroll
    for (int u = 0; u < 4; ++u) {
      unsigned p = pack[j + u];          // padded slot: tail reads safe
      vm[u] = (j + u < end);
      int s = vm[u] ? (int)p : n;
      h[u] = *(const uint2*)(H + ((size_t)s << 6) + (f << 2));
      ss[u] = sS[s];
    }
  }

  for (; j < end; j += 4) {
    const int jn = j + 4;
    uint2 hn[4] = {hs, hs, hs, hs};
    float ssn[4] = {0.f, 0.f, 0.f, 0.f};
    int vn[4] = {0, 0, 0, 0};
    if (jn < end) {  // issue next iteration's loads before consuming current
#pragma unroll
      for (int u = 0; u < 4; ++u) {
        unsigned p = pack[jn + u];
        vn[u] = (jn + u < end);
        int s = vn[u] ? (int)p : n;
        hn[u] = *(const uint2*)(H + ((size_t)s << 6) + (f << 2));
        ssn[u] = sS[s];
      }
    }
    // consume current iteration (registers only)
#pragma unroll
    for (int u = 0; u < 4; ++u) {
      float w = vm[u] ? __expf(lrelu(ss[u] + sDn)) : 0.f;
      den += w;
      a0 += w * bflo(h[u].x);
      a1 += w * bfhi(h[u].x);
      a2 += w * bflo(h[u].y);
      a3 += w * bfhi(h[u].y);
    }
    // rotate pipeline
#pragma unroll
    for (int u = 0; u < 4; ++u) { h[u] = hn[u]; ss[u] = ssn[u]; vm[u] = vn[u]; }
  }

  float v0 = a0 / den + bias[f * 4 + 0];
  float v1 = a1 / den + bias[f * 4 + 1];
  float v2 = a2 / den + bias[f * 4 + 2];
  float v3 = a3 / den + bias[f * 4 + 3];

  if (mode == 0) {
    ushort4 o;
    o.x = f2bf(v0 > 0.f ? v0 : 0.f);
    o.y = f2bf(v1 > 0.f ? v1 : 0.f);
    o.z = f2bf(v2 > 0.f ? v2 : 0.f);
    o.w = f2bf(v3 > 0.f ? v3 : 0.f);
    *(ushort4*)(X1out + (size_t)n * 64 + f * 4) = o;
  } else {
    float sc = v0 * att_c[f * 4 + 0] + v1 * att_c[f * 4 + 1] +
               v2 * att_c[f * 4 + 2] + v3 * att_c[f * 4 + 3];
    sc += __shfl_xor(sc, 1, 16);
    sc += __shfl_xor(sc, 2, 16);
    sc += __shfl_xor(sc, 4, 16);
    sc += __shfl_xor(sc, 8, 16);
    if (first) {
      *(float4*)(O + (size_t)n * 64 + f * 4) = make_float4(v0, v1, v2, v3);
      if (f == 0) { Mn[n] = sc; Sn[n] = 1.f; }
    } else {
      float M = Mn[n];
      float nM = fmaxf(M, sc);
      float scale = __expf(M - nM);
      float wch = __expf(sc - nM);
      float4 o4 = *(const float4*)(O + (size_t)n * 64 + f * 4);
      float o0 = o4.x * scale + wch * v0;
      float o1 = o4.y * scale + wch * v1;
      float o2 = o4.z * scale + wch * v2;
      float o3 = o4.w * scale + wch * v3;
      float s = Sn[n] * scale + wch;
      if (last) {
        *(float4*)(outF + (size_t)n * 64 + f * 4) =
            make_float4(o0 / s, o1 / s, o2 / s, o3 / s);
      } else {
        *(float4*)(O + (size_t)n * 64 + f * 4) = make_float4(o0, o1, o2, o3);
        if (f == 0) { Mn[n] = nM; Sn[n] = s; }
      }
    }
  }
}

// ---------------- host ----------------

extern "C" void kernel_launch(void* const* d_in, const int* in_sizes, int n_in,
                              void* d_out, int out_size, void* d_ws, size_t ws_size,
                              hipStream_t stream) {
  const float* emb = (const float*)d_in[0];
  const float* W1  = (const float*)d_in[1];
  const float* aS1 = (const float*)d_in[2];
  const float* aD1 = (const float*)d_in[3];
  const float* b1  = (const float*)d_in[4];
  const float* W2  = (const float*)d_in[5];
  const float* aS2 = (const float*)d_in[6];
  const float* aD2 = (const float*)d_in[7];
  const float* b2  = (const float*)d_in[8];
  const float* att = (const float*)d_in[9];
  const int*   EI  = (const int*)d_in[10];
  float* out = (float*)d_out;

  const int gElem = (N_NODES * 64) / 256;    // 25000

  // arena ~57.2 MB; ws_size ~288 MB (r6 fillBuffer evidence: 281250 KB)
  const size_t NEEDED = 57500000;
  if (ws_size < NEEDED) {
    write_const<<<gElem, 256, 0, stream>>>(out, 1000.0f + (float)(ws_size >> 20));
    return;
  }

  float* ws = (float*)d_ws;
  size_t off = 0;
  float* sS = ws + off; off += 100000;
  float* sD = ws + off; off += 100000;
  float* Mn = ws + off; off += 100000;
  float* Sn = ws + off; off += 100000;
  unsigned short* Hbf  = (unsigned short*)(ws + off); off += 3200000;  // bf16 H
  unsigned short* X1bf = (unsigned short*)(ws + off); off += 3200000;  // bf16 x1
  int* histM     = (int*)(ws + off);      off += (size_t)NSLOT * MLEN + 64;
  int* bsumA     = (int*)(ws + off);      off += NSLOT * 512;
  int* rp        = (int*)(ws + off);      off += (size_t)NSLOT * NBINS;
  int* perm      = (int*)(ws + off);      off += (size_t)NSLOT * NBINS;
  int* histPM    = (int*)(ws + off);      off += (size_t)NSLOT * PMLEN + 64;
  unsigned* pack = (unsigned*)(ws + off); off += (size_t)NSLOT * PACK_STRIDE;

  const int gGemm = (N_NODES + 127) / 128;   // 782
  const int gRow  = N_NODES / 16;            // 6250
  // O accumulator for the channel combine lives in d_out (write-only until
  // first channel's layer-1 aggregate writes it unconditionally).

  auto build = [&](int base, int nG) {
    histA<<<dim3(NBLK, nG), 256, 0, stream>>>(EI, base, histM);
    scanA1<<<dim3(NBA1, nG), 256, 0, stream>>>(histM, bsumA);
    scanA2<<<nG, 512, 0, stream>>>(bsumA);
    scanA3<<<dim3(NBA1, nG), 256, 0, stream>>>(histM, bsumA);
    scatterA<<<dim3(NBLK, nG), 256, 0, stream>>>(EI, base, histM, pack);
    sortB<<<dim3(NBUCK, nG), 256, 0, stream>>>(histM, pack, rp);
    histP<<<dim3(NPBLK, nG), 256, 0, stream>>>(rp, histPM);
    scanP<<<nG, 512, 0, stream>>>(histPM);
    scatterP<<<dim3(NPBLK, nG), 256, 0, stream>>>(rp, histPM, perm);
  };

  build(0, 8);                  // graphs 0..7  -> channels 0..3

  for (int c = 0; c < N_CH; ++c) {
    if (c == 4) build(8, 10);   // graphs 8..17 -> channels 4..8 (slots reused)

    for (int layer = 0; layer < 2; ++layer) {
      const int gi = c * 2 + layer;
      const int slot = (gi < 8) ? gi : gi - 8;

      const float* Wf = (layer == 0) ? W1 + (size_t)c * 4096 : W2 + (size_t)c * 4096;
      const float* aS = (layer == 0) ? aS1 + c * 64 : aS2 + c * 64;
      const float* aD = (layer == 0) ? aD1 + c * 64 : aD2 + c * 64;
      const float* bb = (layer == 0) ? b1 + c * 64 : b2 + c * 64;

      if (layer == 0)
        gemm64_f32<<<gGemm, 256, 0, stream>>>(emb, Wf, aS, aD, Hbf, sS, sD, N_NODES);
      else
        gemm64_bf<<<gGemm, 256, 0, stream>>>(X1bf, Wf, aS, aD, Hbf, sS, sD, N_NODES);

      aggregate<<<gRow, 256, 0, stream>>>(Hbf, sS, sD,
                                          rp + (size_t)slot * NBINS,
                                          perm + (size_t)slot * NBINS,
                                          pack + (size_t)slot * PACK_STRIDE,
                                          bb, X1bf, att + c * 64,
                                          out, Mn, Sn, out,
                                          layer, (c == 0) ? 1 : 0, (c == N_CH - 1) ? 1 : 0);
    }
  }
}

// Round 11
// 1073.547 us; speedup vs baseline: 1.0398x; 1.0398x over previous
//
#include <hip/hip_runtime.h>
#include <hip/hip_bf16.h>
#include <math.h>

#define N_NODES   100000
#define N_CH      9
#define N_EDG     500000
#define NEG_SLOPE 0.2f
#define NBINS     N_NODES
#define NSLOT     10           // structure slots (batch2 = 10 graphs)
#define PACK_STRIDE 500016     // u32 per graph slot (+16 pad for tail reads)

// bucket sort geometry (r4-verified)
#define CHUNK  4096            // edges per block in histA/scatterA
#define NBLK   123             // ceil(500000/4096)
#define NBUCK  391             // buckets of 256 nodes: dst>>8
#define MLEN   (NBUCK * NBLK)  // 48093 matrix entries per graph
#define NBA1   188             // ceil(MLEN/256) scan blocks
#define BCAP   4096            // LDS capacity per bucket (mean 1280, sigma~36)

// ---------------- utility ----------------

__device__ __forceinline__ float bf2f(unsigned short h) {
  return __uint_as_float(((unsigned)h) << 16);
}
// bf16 pair unpack straight from a u32 (lo = elem 2k, hi = elem 2k+1)
__device__ __forceinline__ float bflo(unsigned u) { return __uint_as_float(u << 16); }
__device__ __forceinline__ float bfhi(unsigned u) { return __uint_as_float(u & 0xffff0000u); }
__device__ __forceinline__ unsigned short f2bf(float f) {
  unsigned u = __float_as_uint(f);
  u += 0x7FFFu + ((u >> 16) & 1u);
  return (unsigned short)(u >> 16);
}
__device__ __forceinline__ float lrelu(float x) { return x > 0.f ? x : NEG_SLOPE * x; }
__device__ __forceinline__ int clampi(int x) {
  return x < 0 ? 0 : (x >= N_NODES ? N_NODES - 1 : x);
}

// ---------------- diagnostic: fill output with a constant (f32) ------------
__global__ __launch_bounds__(256) void write_const(float* __restrict__ out, float val) {
  int idx = blockIdx.x * 256 + threadIdx.x;
  out[idx] = val;
}

// ---------------- GEMM + fused attention dots ------------------------------
// H[M,64](bf16) = A[M,64] @ W[64,64](f32); also sS = H.a_src, sD = H.a_dst.
// 256 thr, 128 rows/block, 8x4 thread tile.
// r10: redS/redD ALIAS the Xs buffer (Xs is dead after the K-loop) -> LDS
// 67.6 KB -> 49 KB -> 3 blocks/CU instead of 2 (+50% waves for latency
// hiding).  One extra __syncthreads() separates the last Xs read from the
// first redS write.
#define GEMM_BODY(LOAD_A)                                                     \
  __shared__ float Ws[64 * 64];                                               \
  __shared__ float XsRed[64 * 132];   /* Xs during K-loop; redS/redD after */ \
  float* const Xs = XsRed;                                                    \
  float* const redS = XsRed;                /* [128][17], 2-way conflicts */  \
  float* const redD = XsRed + 128 * 17;                                       \
  const int tx = threadIdx.x;                                                 \
  const int r0 = blockIdx.x * 128;                                            \
  _Pragma("unroll")                                                           \
  for (int i = 0; i < 16; ++i) Ws[tx + 256 * i] = W[tx + 256 * i];            \
  _Pragma("unroll")                                                           \
  for (int it = 0; it < 8; ++it) {                                            \
    int f = tx + 256 * it;                                                    \
    int r = f >> 4;                                                           \
    int k0 = (f & 15) << 2;                                                   \
    float4 v = make_float4(0.f, 0.f, 0.f, 0.f);                               \
    if (r0 + r < M) { LOAD_A }                                                \
    Xs[(k0 + 0) * 132 + r] = v.x;                                             \
    Xs[(k0 + 1) * 132 + r] = v.y;                                             \
    Xs[(k0 + 2) * 132 + r] = v.z;                                             \
    Xs[(k0 + 3) * 132 + r] = v.w;                                             \
  }                                                                           \
  __syncthreads();                                                            \
  const int cg = tx & 15, rg = tx >> 4;                                       \
  float acc[8][4];                                                            \
  _Pragma("unroll")                                                           \
  for (int i = 0; i < 8; ++i)                                                 \
    _Pragma("unroll")                                                         \
    for (int j = 0; j < 4; ++j) acc[i][j] = 0.f;                              \
  _Pragma("unroll 4")                                                         \
  for (int k = 0; k < 64; ++k) {                                              \
    float4 w4 = *(const float4*)(Ws + k * 64 + cg * 4);                       \
    float4 x0 = *(const float4*)(Xs + k * 132 + rg * 8);                      \
    float4 x1 = *(const float4*)(Xs + k * 132 + rg * 8 + 4);                  \
    float xr[8] = {x0.x, x0.y, x0.z, x0.w, x1.x, x1.y, x1.z, x1.w};           \
    float wr[4] = {w4.x, w4.y, w4.z, w4.w};                                   \
    _Pragma("unroll")                                                         \
    for (int i = 0; i < 8; ++i)                                               \
      _Pragma("unroll")                                                       \
      for (int j = 0; j < 4; ++j) acc[i][j] += xr[i] * wr[j];                 \
  }                                                                           \
  __syncthreads();   /* Xs dead from here: safe to reuse as redS/redD */      \
  float4 s4 = *(const float4*)(a_src + cg * 4);                               \
  float4 d4 = *(const float4*)(a_dst + cg * 4);                               \
  _Pragma("unroll")                                                           \
  for (int i = 0; i < 8; ++i) {                                               \
    int row = rg * 8 + i;                                                     \
    redS[row * 17 + cg] =                                                     \
        acc[i][0] * s4.x + acc[i][1] * s4.y + acc[i][2] * s4.z + acc[i][3] * s4.w; \
    redD[row * 17 + cg] =                                                     \
        acc[i][0] * d4.x + acc[i][1] * d4.y + acc[i][2] * d4.z + acc[i][3] * d4.w; \
    int r = r0 + row;                                                         \
    if (r < M) {                                                              \
      ushort4 o;                                                              \
      o.x = f2bf(acc[i][0]); o.y = f2bf(acc[i][1]);                           \
      o.z = f2bf(acc[i][2]); o.w = f2bf(acc[i][3]);                           \
      *(ushort4*)(Hout + (size_t)r * 64 + cg * 4) = o;                        \
    }                                                                         \
  }                                                                           \
  __syncthreads();                                                            \
  if (tx < 128) {                                                             \
    float s = 0.f;                                                            \
    _Pragma("unroll")                                                         \
    for (int c2 = 0; c2 < 16; ++c2) s += redS[tx * 17 + c2];                  \
    if (r0 + tx < M) sS[r0 + tx] = s;                                         \
  } else {                                                                    \
    int row = tx - 128;                                                       \
    float s = 0.f;                                                            \
    _Pragma("unroll")                                                         \
    for (int c2 = 0; c2 < 16; ++c2) s += redD[row * 17 + c2];                 \
    if (r0 + row < M) sD[r0 + row] = s;                                       \
  }

__global__ __launch_bounds__(256) void gemm64_f32(const float* __restrict__ A,
                                                  const float* __restrict__ W,
                                                  const float* __restrict__ a_src,
                                                  const float* __restrict__ a_dst,
                                                  unsigned short* __restrict__ Hout,
                                                  float* __restrict__ sS,
                                                  float* __restrict__ sD, int M) {
  GEMM_BODY(v = *(const float4*)(A + (size_t)(r0 + r) * 64 + k0);)
}

__global__ __launch_bounds__(256) void gemm64_bf(const unsigned short* __restrict__ A,
                                                 const float* __restrict__ W,
                                                 const float* __restrict__ a_src,
                                                 const float* __restrict__ a_dst,
                                                 unsigned short* __restrict__ Hout,
                                                 float* __restrict__ sS,
                                                 float* __restrict__ sD, int M) {
  GEMM_BODY(ushort4 h = *(const ushort4*)(A + (size_t)(r0 + r) * 64 + k0);
            v.x = bf2f(h.x); v.y = bf2f(h.y); v.z = bf2f(h.z); v.w = bf2f(h.w);)
}

// ---------------- batched CSR build: atomic-free two-level bucket sort -----
// (r4-verified structure)

__global__ __launch_bounds__(256) void histA(const int* __restrict__ EI, int base,
                                             int* __restrict__ histM) {
  const int g = blockIdx.y;
  const int* dst = EI + ((size_t)(base + g) * 2 + 1) * N_EDG;
  __shared__ int h[NBUCK];
  for (int i = threadIdx.x; i < NBUCK; i += 256) h[i] = 0;
  __syncthreads();
  const int e0 = blockIdx.x * CHUNK;
#pragma unroll
  for (int k = 0; k < CHUNK; k += 256) {
    int i = e0 + k + threadIdx.x;
    if (i < N_EDG) atomicAdd(&h[clampi(dst[i]) >> 8], 1);
  }
  __syncthreads();
  for (int i = threadIdx.x; i < NBUCK; i += 256)
    histM[(size_t)g * MLEN + i * NBLK + blockIdx.x] = h[i];
}

__global__ __launch_bounds__(256) void scanA1(int* __restrict__ data,
                                              int* __restrict__ bsum) {
  const int g = blockIdx.y;
  __shared__ int sh[256];
  int i = blockIdx.x * 256 + threadIdx.x;
  int x = (i < MLEN) ? data[(size_t)g * MLEN + i] : 0;
  sh[threadIdx.x] = x;
  __syncthreads();
  for (int off = 1; off < 256; off <<= 1) {
    int t = (threadIdx.x >= off) ? sh[threadIdx.x - off] : 0;
    __syncthreads();
    sh[threadIdx.x] += t;
    __syncthreads();
  }
  if (i < MLEN) data[(size_t)g * MLEN + i] = sh[threadIdx.x] - x;  // exclusive
  if (threadIdx.x == 255) bsum[g * 512 + blockIdx.x] = sh[255];
}

__global__ __launch_bounds__(512) void scanA2(int* __restrict__ bsum) {
  const int g = blockIdx.x;
  __shared__ int sh[512];
  int x = (threadIdx.x < NBA1) ? bsum[g * 512 + threadIdx.x] : 0;
  sh[threadIdx.x] = x;
  __syncthreads();
  for (int off = 1; off < 512; off <<= 1) {
    int t = (threadIdx.x >= off) ? sh[threadIdx.x - off] : 0;
    __syncthreads();
    sh[threadIdx.x] += t;
    __syncthreads();
  }
  if (threadIdx.x < NBA1) bsum[g * 512 + threadIdx.x] = sh[threadIdx.x] - x;  // exclusive
}

__global__ void scanA3(int* __restrict__ data, const int* __restrict__ bsum) {
  const int g = blockIdx.y;
  int i = blockIdx.x * 256 + threadIdx.x;
  if (i < MLEN) data[(size_t)g * MLEN + i] += bsum[g * 512 + blockIdx.x];
}

// block-local counting sort by coarse bucket + coalesced sequential writeout.
__global__ __launch_bounds__(256) void scatterA(const int* __restrict__ EI, int base,
                                                const int* __restrict__ histM,
                                                unsigned* __restrict__ pack) {
  const int g = blockIdx.y;
  const int* srcp = EI + ((size_t)(base + g) * 2 + 0) * N_EDG;
  const int* dstp = EI + ((size_t)(base + g) * 2 + 1) * N_EDG;
  __shared__ unsigned ed[CHUNK];          // 16 KB: bucket-grouped entries
  __shared__ unsigned short bkt[CHUNK];   // 8 KB: bucket id per slot
  __shared__ int lcnt[NBUCK];
  __shared__ int ebase[NBUCK];
  __shared__ int gbase[NBUCK];
  __shared__ int sc[512];
  const int t = threadIdx.x;
  const int e0 = blockIdx.x * CHUNK;
  const int nE = (N_EDG - e0 < CHUNK) ? (N_EDG - e0) : CHUNK;

  for (int i = t; i < NBUCK; i += 256) {
    lcnt[i] = 0;
    gbase[i] = histM[(size_t)g * MLEN + i * NBLK + blockIdx.x];
  }
  __syncthreads();
  // pass 1: local histogram (reads dst; stays hot in L1/L2 for pass 2)
  for (int k = t; k < nE; k += 256)
    atomicAdd(&lcnt[clampi(dstp[e0 + k]) >> 8], 1);
  __syncthreads();
  // block-wide inclusive scan of 512-padded lcnt (each thread owns 2 slots)
  int v0 = (t < NBUCK) ? lcnt[t] : 0;
  int v1 = (t + 256 < NBUCK) ? lcnt[t + 256] : 0;
  sc[t] = v0; sc[t + 256] = v1;
  __syncthreads();
  for (int off = 1; off < 512; off <<= 1) {
    int a0 = (t >= off) ? sc[t - off] : 0;
    int a1 = (t + 256 >= off) ? sc[t + 256 - off] : 0;
    __syncthreads();
    sc[t] += a0; sc[t + 256] += a1;
    __syncthreads();
  }
  if (t < NBUCK)       { ebase[t] = sc[t] - v0;             lcnt[t] = 0; }
  if (t + 256 < NBUCK) { ebase[t + 256] = sc[t + 256] - v1; lcnt[t + 256] = 0; }
  __syncthreads();
  // pass 2: scatter into LDS, bucket-grouped (rank via LDS atomics)
  for (int k = t; k < nE; k += 256) {
    int d = clampi(dstp[e0 + k]);
    int s = clampi(srcp[e0 + k]);
    int b = d >> 8;
    int slot = ebase[b] + atomicAdd(&lcnt[b], 1);
    ed[slot] = ((unsigned)s << 8) | (unsigned)(d & 255);
    bkt[slot] = (unsigned short)b;
  }
  __syncthreads();
  // pass 3: sequential write-out -> bucket-runs leave as consecutive lanes
  unsigned* pk = pack + (size_t)g * PACK_STRIDE;
  for (int i = t; i < nE; i += 256) {
    int b = bkt[i];
    pk[gbase[b] + (i - ebase[b])] = ed[i];
  }
}

__global__ __launch_bounds__(256) void sortB(const int* __restrict__ histM,
                                             unsigned* __restrict__ pack,
                                             int* __restrict__ rp) {
  const int g = blockIdx.y;
  const int b = blockIdx.x;   // bucket 0..390
  __shared__ unsigned ed[BCAP];
  __shared__ unsigned ed2[BCAP];
  __shared__ int cnt[256];
  __shared__ int sh[256];
  const int t = threadIdx.x;
  const int beg = histM[(size_t)g * MLEN + b * NBLK];
  const int end = (b + 1 < NBUCK) ? histM[(size_t)g * MLEN + (b + 1) * NBLK] : N_EDG;
  int m = end - beg;
  if (m > BCAP) m = BCAP;   // defensive: statistically impossible (78 sigma)
  unsigned* pk = pack + (size_t)g * PACK_STRIDE;

  cnt[t] = 0;
  __syncthreads();
  for (int i = t; i < m; i += 256) {
    unsigned w = pk[beg + i];
    ed[i] = w;
    atomicAdd(&cnt[w & 255u], 1);
  }
  __syncthreads();
  // block-wide Hillis-Steele inclusive scan of cnt -> sh
  int x = cnt[t];
  sh[t] = x;
  __syncthreads();
  for (int off = 1; off < 256; off <<= 1) {
    int tt = (t >= off) ? sh[t - off] : 0;
    __syncthreads();
    sh[t] += tt;
    __syncthreads();
  }
  // rp end-offsets for this bucket's nodes (global edge indexing)
  int n = b * 256 + t;
  if (n < N_NODES) rp[(size_t)g * NBINS + n] = beg + sh[t];
  // cursor = exclusive base
  cnt[t] = sh[t] - x;
  __syncthreads();
  // counting-sort scatter within LDS (order within a node is irrelevant)
  for (int i = t; i < m; i += 256) {
    unsigned w = ed[i];
    int pos = atomicAdd(&cnt[w & 255u], 1);
    ed2[pos] = w >> 8;                    // keep src only
  }
  __syncthreads();
  // in-place, fully coalesced write-back of dst-sorted src list
  for (int i = t; i < m; i += 256) pk[beg + i] = ed2[i];
}

// ---------------- per-node GAT aggregation (16 lanes per node) -------------
// Lane f = tx&15 permanently owns features 4f..4f+3 (no reduction shuffles).
// 4 edges per iteration, SOFTWARE-PIPELINED one iteration ahead: iteration i
// issues iteration i+1's pack load and its dependent H/sS gathers, then
// consumes iteration i's already-resident registers (exp + FMA only).
// Linear node assignment keeps all outputs coalesced (r9 lesson: permuted
// node ids cost more in scattered 64B writes than divergence savings).
// mode 0: X1=bf16(relu(v)); mode 1: online channel combine (O,Mn,Sn).
__global__ __launch_bounds__(256) void aggregate(const unsigned short* __restrict__ H,
                                                 const float* __restrict__ sS,
                                                 const float* __restrict__ sD,
                                                 const int* __restrict__ rp,  // end offsets
                                                 const unsigned* __restrict__ pack,
                                                 const float* __restrict__ bias,
                                                 unsigned short* __restrict__ X1out,
                                                 const float* __restrict__ att_c,
                                                 float* __restrict__ O,
                                                 float* __restrict__ Mn,
                                                 float* __restrict__ Sn,
                                                 float* __restrict__ outF,
                                                 int mode, int first, int last) {
  const int n = blockIdx.x * 16 + (threadIdx.x >> 4);
  const int f = threadIdx.x & 15;       // feature quad: feats 4f..4f+3
  const int beg = (n == 0) ? 0 : rp[n - 1];
  const int end = rp[n];
  const float sDn = sD[n];
  const float wself = __expf(lrelu(sS[n] + sDn));

  // self loop
  uint2 hs = *(const uint2*)(H + ((size_t)n << 6) + (f << 2));
  float a0 = wself * bflo(hs.x);
  float a1 = wself * bfhi(hs.x);
  float a2 = wself * bflo(hs.y);
  float a3 = wself * bfhi(hs.y);
  float den = wself;

  // pipeline registers for the current iteration
  uint2 h[4];
  float ss[4];
  int vm[4];
  int j = beg;
  if (j < end) {
#pragma unroll
    for (int u = 0; u < 4; ++u) {
      unsigned p = pack[j + u];          // padded slot: tail reads safe
      vm[u] = (j + u < end);
      int s = vm[u] ? (int)p : n;
      h[u] = *(const uint2*)(H + ((size_t)s << 6) + (f << 2));
      ss[u] = sS[s];
    }
  }

  for (; j < end; j += 4) {
    const int jn = j + 4;
    uint2 hn[4] = {hs, hs, hs, hs};
    float ssn[4] = {0.f, 0.f, 0.f, 0.f};
    int vn[4] = {0, 0, 0, 0};
    if (jn < end) {  // issue next iteration's loads before consuming current
#pragma unroll
      for (int u = 0; u < 4; ++u) {
        unsigned p = pack[jn + u];
        vn[u] = (jn + u < end);
        int s = vn[u] ? (int)p : n;
        hn[u] = *(const uint2*)(H + ((size_t)s << 6) + (f << 2));
        ssn[u] = sS[s];
      }
    }
    // consume current iteration (registers only)
#pragma unroll
    for (int u = 0; u < 4; ++u) {
      float w = vm[u] ? __expf(lrelu(ss[u] + sDn)) : 0.f;
      den += w;
      a0 += w * bflo(h[u].x);
      a1 += w * bfhi(h[u].x);
      a2 += w * bflo(h[u].y);
      a3 += w * bfhi(h[u].y);
    }
    // rotate pipeline
#pragma unroll
    for (int u = 0; u < 4; ++u) { h[u] = hn[u]; ss[u] = ssn[u]; vm[u] = vn[u]; }
  }

  float v0 = a0 / den + bias[f * 4 + 0];
  float v1 = a1 / den + bias[f * 4 + 1];
  float v2 = a2 / den + bias[f * 4 + 2];
  float v3 = a3 / den + bias[f * 4 + 3];

  if (mode == 0) {
    ushort4 o;
    o.x = f2bf(v0 > 0.f ? v0 : 0.f);
    o.y = f2bf(v1 > 0.f ? v1 : 0.f);
    o.z = f2bf(v2 > 0.f ? v2 : 0.f);
    o.w = f2bf(v3 > 0.f ? v3 : 0.f);
    *(ushort4*)(X1out + (size_t)n * 64 + f * 4) = o;
  } else {
    float sc = v0 * att_c[f * 4 + 0] + v1 * att_c[f * 4 + 1] +
               v2 * att_c[f * 4 + 2] + v3 * att_c[f * 4 + 3];
    sc += __shfl_xor(sc, 1, 16);
    sc += __shfl_xor(sc, 2, 16);
    sc += __shfl_xor(sc, 4, 16);
    sc += __shfl_xor(sc, 8, 16);
    if (first) {
      *(float4*)(O + (size_t)n * 64 + f * 4) = make_float4(v0, v1, v2, v3);
      if (f == 0) { Mn[n] = sc; Sn[n] = 1.f; }
    } else {
      float M = Mn[n];
      float nM = fmaxf(M, sc);
      float scale = __expf(M - nM);
      float wch = __expf(sc - nM);
      float4 o4 = *(const float4*)(O + (size_t)n * 64 + f * 4);
      float o0 = o4.x * scale + wch * v0;
      float o1 = o4.y * scale + wch * v1;
      float o2 = o4.z * scale + wch * v2;
      float o3 = o4.w * scale + wch * v3;
      float s = Sn[n] * scale + wch;
      if (last) {
        *(float4*)(outF + (size_t)n * 64 + f * 4) =
            make_float4(o0 / s, o1 / s, o2 / s, o3 / s);
      } else {
        *(float4*)(O + (size_t)n * 64 + f * 4) = make_float4(o0, o1, o2, o3);
        if (f == 0) { Mn[n] = nM; Sn[n] = s; }
      }
    }
  }
}

// ---------------- host ----------------

extern "C" void kernel_launch(void* const* d_in, const int* in_sizes, int n_in,
                              void* d_out, int out_size, void* d_ws, size_t ws_size,
                              hipStream_t stream) {
  const float* emb = (const float*)d_in[0];
  const float* W1  = (const float*)d_in[1];
  const float* aS1 = (const float*)d_in[2];
  const float* aD1 = (const float*)d_in[3];
  const float* b1  = (const float*)d_in[4];
  const float* W2  = (const float*)d_in[5];
  const float* aS2 = (const float*)d_in[6];
  const float* aD2 = (const float*)d_in[7];
  const float* b2  = (const float*)d_in[8];
  const float* att = (const float*)d_in[9];
  const int*   EI  = (const int*)d_in[10];
  float* out = (float*)d_out;

  const int gElem = (N_NODES * 64) / 256;    // 25000

  // arena ~53.15 MB; ws_size ~288 MB (r6 fillBuffer evidence)
  const size_t NEEDED = 53200000;
  if (ws_size < NEEDED) {
    write_const<<<gElem, 256, 0, stream>>>(out, 1000.0f + (float)(ws_size >> 20));
    return;
  }

  float* ws = (float*)d_ws;
  size_t off = 0;
  float* sS = ws + off; off += 100000;
  float* sD = ws + off; off += 100000;
  float* Mn = ws + off; off += 100000;
  float* Sn = ws + off; off += 100000;
  unsigned short* Hbf  = (unsigned short*)(ws + off); off += 3200000;  // bf16 H
  unsigned short* X1bf = (unsigned short*)(ws + off); off += 3200000;  // bf16 x1
  int* histM     = (int*)(ws + off);      off += (size_t)NSLOT * MLEN + 64;
  int* bsumA     = (int*)(ws + off);      off += NSLOT * 512;
  int* rp        = (int*)(ws + off);      off += (size_t)NSLOT * NBINS;
  unsigned* pack = (unsigned*)(ws + off); off += (size_t)NSLOT * PACK_STRIDE;

  const int gGemm = (N_NODES + 127) / 128;   // 782
  const int gRow  = N_NODES / 16;            // 6250
  // O accumulator for the channel combine lives in d_out (write-only until
  // first channel's layer-1 aggregate writes it unconditionally).

  auto build = [&](int base, int nG) {
    histA<<<dim3(NBLK, nG), 256, 0, stream>>>(EI, base, histM);
    scanA1<<<dim3(NBA1, nG), 256, 0, stream>>>(histM, bsumA);
    scanA2<<<nG, 512, 0, stream>>>(bsumA);
    scanA3<<<dim3(NBA1, nG), 256, 0, stream>>>(histM, bsumA);
    scatterA<<<dim3(NBLK, nG), 256, 0, stream>>>(EI, base, histM, pack);
    sortB<<<dim3(NBUCK, nG), 256, 0, stream>>>(histM, pack, rp);
  };

  build(0, 8);                  // graphs 0..7  -> channels 0..3

  for (int c = 0; c < N_CH; ++c) {
    if (c == 4) build(8, 10);   // graphs 8..17 -> channels 4..8 (slots reused)

    for (int layer = 0; layer < 2; ++layer) {
      const int gi = c * 2 + layer;
      const int slot = (gi < 8) ? gi : gi - 8;

      const float* Wf = (layer == 0) ? W1 + (size_t)c * 4096 : W2 + (size_t)c * 4096;
      const float* aS = (layer == 0) ? aS1 + c * 64 : aS2 + c * 64;
      const float* aD = (layer == 0) ? aD1 + c * 64 : aD2 + c * 64;
      const float* bb = (layer == 0) ? b1 + c * 64 : b2 + c * 64;

      if (layer == 0)
        gemm64_f32<<<gGemm, 256, 0, stream>>>(emb, Wf, aS, aD, Hbf, sS, sD, N_NODES);
      else
        gemm64_bf<<<gGemm, 256, 0, stream>>>(X1bf, Wf, aS, aD, Hbf, sS, sD, N_NODES);

      aggregate<<<gRow, 256, 0, stream>>>(Hbf, sS, sD,
                                          rp + (size_t)slot * NBINS,
                                          pack + (size_t)slot * PACK_STRIDE,
                                          bb, X1bf, att + c * 64,
                                          out, Mn, Sn, out,
                                          layer, (c == 0) ? 1 : 0, (c == N_CH - 1) ? 1 : 0);
    }
  }
}

// Round 12
// 1046.735 us; speedup vs baseline: 1.0664x; 1.0256x over previous
//
#include <hip/hip_runtime.h>
#include <hip/hip_bf16.h>
#include <math.h>

#define N_NODES   100000
#define N_CH      9
#define N_EDG     500000
#define NEG_SLOPE 0.2f
#define NBINS     N_NODES
#define NSLOT     18           // ALL graph structures built once (ws=288MB proven)
#define PACK_STRIDE 500016     // u32 per graph slot (+16 pad for tail reads)

// bucket sort geometry (r4-verified)
#define CHUNK  4096            // edges per block in histA/scatterA
#define NBLK   123             // ceil(500000/4096)
#define NBUCK  391             // buckets of 256 nodes: dst>>8
#define MLEN   (NBUCK * NBLK)  // 48093 matrix entries per graph
#define NBA1   188             // ceil(MLEN/256) scan blocks
#define BCAP   4096            // LDS capacity per bucket (mean 1280, sigma~36)

// ---------------- utility ----------------

__device__ __forceinline__ float bf2f(unsigned short h) {
  return __uint_as_float(((unsigned)h) << 16);
}
// bf16 pair unpack straight from a u32 (lo = elem 2k, hi = elem 2k+1)
__device__ __forceinline__ float bflo(unsigned u) { return __uint_as_float(u << 16); }
__device__ __forceinline__ float bfhi(unsigned u) { return __uint_as_float(u & 0xffff0000u); }
__device__ __forceinline__ unsigned short f2bf(float f) {
  unsigned u = __float_as_uint(f);
  u += 0x7FFFu + ((u >> 16) & 1u);
  return (unsigned short)(u >> 16);
}
__device__ __forceinline__ float lrelu(float x) { return x > 0.f ? x : NEG_SLOPE * x; }
__device__ __forceinline__ int clampi(int x) {
  return x < 0 ? 0 : (x >= N_NODES ? N_NODES - 1 : x);
}

// ---------------- diagnostic: fill output with a constant (f32) ------------
__global__ __launch_bounds__(256) void write_const(float* __restrict__ out, float val) {
  int idx = blockIdx.x * 256 + threadIdx.x;
  out[idx] = val;
}

// ---------------- GEMM + fused attention dots ------------------------------
// H[M,64](bf16) = A[M,64] @ W[64,64](f32); also sS = H.a_src, sD = H.a_dst.
// 256 thr, 128 rows/block, 8x4 thread tile.
// r10: redS/redD ALIAS the Xs buffer (Xs is dead after the K-loop) -> LDS
// 67.6 KB -> 49 KB -> 3 blocks/CU instead of 2.
#define GEMM_BODY(LOAD_A)                                                     \
  __shared__ float Ws[64 * 64];                                               \
  __shared__ float XsRed[64 * 132];   /* Xs during K-loop; redS/redD after */ \
  float* const Xs = XsRed;                                                    \
  float* const redS = XsRed;                /* [128][17], 2-way conflicts */  \
  float* const redD = XsRed + 128 * 17;                                       \
  const int tx = threadIdx.x;                                                 \
  const int r0 = blockIdx.x * 128;                                            \
  _Pragma("unroll")                                                           \
  for (int i = 0; i < 16; ++i) Ws[tx + 256 * i] = W[tx + 256 * i];            \
  _Pragma("unroll")                                                           \
  for (int it = 0; it < 8; ++it) {                                            \
    int f = tx + 256 * it;                                                    \
    int r = f >> 4;                                                           \
    int k0 = (f & 15) << 2;                                                   \
    float4 v = make_float4(0.f, 0.f, 0.f, 0.f);                               \
    if (r0 + r < M) { LOAD_A }                                                \
    Xs[(k0 + 0) * 132 + r] = v.x;                                             \
    Xs[(k0 + 1) * 132 + r] = v.y;                                             \
    Xs[(k0 + 2) * 132 + r] = v.z;                                             \
    Xs[(k0 + 3) * 132 + r] = v.w;                                             \
  }                                                                           \
  __syncthreads();                                                            \
  const int cg = tx & 15, rg = tx >> 4;                                       \
  float acc[8][4];                                                            \
  _Pragma("unroll")                                                           \
  for (int i = 0; i < 8; ++i)                                                 \
    _Pragma("unroll")                                                         \
    for (int j = 0; j < 4; ++j) acc[i][j] = 0.f;                              \
  _Pragma("unroll 4")                                                         \
  for (int k = 0; k < 64; ++k) {                                              \
    float4 w4 = *(const float4*)(Ws + k * 64 + cg * 4);                       \
    float4 x0 = *(const float4*)(Xs + k * 132 + rg * 8);                      \
    float4 x1 = *(const float4*)(Xs + k * 132 + rg * 8 + 4);                  \
    float xr[8] = {x0.x, x0.y, x0.z, x0.w, x1.x, x1.y, x1.z, x1.w};           \
    float wr[4] = {w4.x, w4.y, w4.z, w4.w};                                   \
    _Pragma("unroll")                                                         \
    for (int i = 0; i < 8; ++i)                                               \
      _Pragma("unroll")                                                       \
      for (int j = 0; j < 4; ++j) acc[i][j] += xr[i] * wr[j];                 \
  }                                                                           \
  __syncthreads();   /* Xs dead from here: safe to reuse as redS/redD */      \
  float4 s4 = *(const float4*)(a_src + cg * 4);                               \
  float4 d4 = *(const float4*)(a_dst + cg * 4);                               \
  _Pragma("unroll")                                                           \
  for (int i = 0; i < 8; ++i) {                                               \
    int row = rg * 8 + i;                                                     \
    redS[row * 17 + cg] =                                                     \
        acc[i][0] * s4.x + acc[i][1] * s4.y + acc[i][2] * s4.z + acc[i][3] * s4.w; \
    redD[row * 17 + cg] =                                                     \
        acc[i][0] * d4.x + acc[i][1] * d4.y + acc[i][2] * d4.z + acc[i][3] * d4.w; \
    int r = r0 + row;                                                         \
    if (r < M) {                                                              \
      ushort4 o;                                                              \
      o.x = f2bf(acc[i][0]); o.y = f2bf(acc[i][1]);                           \
      o.z = f2bf(acc[i][2]); o.w = f2bf(acc[i][3]);                           \
      *(ushort4*)(Hout + (size_t)r * 64 + cg * 4) = o;                        \
    }                                                                         \
  }                                                                           \
  __syncthreads();                                                            \
  if (tx < 128) {                                                             \
    float s = 0.f;                                                            \
    _Pragma("unroll")                                                         \
    for (int c2 = 0; c2 < 16; ++c2) s += redS[tx * 17 + c2];                  \
    if (r0 + tx < M) sS[r0 + tx] = s;                                         \
  } else {                                                                    \
    int row = tx - 128;                                                       \
    float s = 0.f;                                                            \
    _Pragma("unroll")                                                         \
    for (int c2 = 0; c2 < 16; ++c2) s += redD[row * 17 + c2];                 \
    if (r0 + row < M) sD[r0 + row] = s;                                       \
  }

__global__ __launch_bounds__(256) void gemm64_f32(const float* __restrict__ A,
                                                  const float* __restrict__ W,
                                                  const float* __restrict__ a_src,
                                                  const float* __restrict__ a_dst,
                                                  unsigned short* __restrict__ Hout,
                                                  float* __restrict__ sS,
                                                  float* __restrict__ sD, int M) {
  GEMM_BODY(v = *(const float4*)(A + (size_t)(r0 + r) * 64 + k0);)
}

__global__ __launch_bounds__(256) void gemm64_bf(const unsigned short* __restrict__ A,
                                                 const float* __restrict__ W,
                                                 const float* __restrict__ a_src,
                                                 const float* __restrict__ a_dst,
                                                 unsigned short* __restrict__ Hout,
                                                 float* __restrict__ sS,
                                                 float* __restrict__ sD, int M) {
  GEMM_BODY(ushort4 h = *(const ushort4*)(A + (size_t)(r0 + r) * 64 + k0);
            v.x = bf2f(h.x); v.y = bf2f(h.y); v.z = bf2f(h.z); v.w = bf2f(h.w);)
}

// ---------------- batched CSR build: atomic-free two-level bucket sort -----
// r12: ONE build over all 18 graphs (ws=288MB proven r6/r11; the old 2-batch
// split dated from a 56MB assumption).  Halves build launches, pays the
// grid ramp/drain once, and removes the mid-loop build stall at c==4.

__global__ __launch_bounds__(256) void histA(const int* __restrict__ EI, int base,
                                             int* __restrict__ histM) {
  const int g = blockIdx.y;
  const int* dst = EI + ((size_t)(base + g) * 2 + 1) * N_EDG;
  __shared__ int h[NBUCK];
  for (int i = threadIdx.x; i < NBUCK; i += 256) h[i] = 0;
  __syncthreads();
  const int e0 = blockIdx.x * CHUNK;
#pragma unroll
  for (int k = 0; k < CHUNK; k += 256) {
    int i = e0 + k + threadIdx.x;
    if (i < N_EDG) atomicAdd(&h[clampi(dst[i]) >> 8], 1);
  }
  __syncthreads();
  for (int i = threadIdx.x; i < NBUCK; i += 256)
    histM[(size_t)g * MLEN + i * NBLK + blockIdx.x] = h[i];
}

__global__ __launch_bounds__(256) void scanA1(int* __restrict__ data,
                                              int* __restrict__ bsum) {
  const int g = blockIdx.y;
  __shared__ int sh[256];
  int i = blockIdx.x * 256 + threadIdx.x;
  int x = (i < MLEN) ? data[(size_t)g * MLEN + i] : 0;
  sh[threadIdx.x] = x;
  __syncthreads();
  for (int off = 1; off < 256; off <<= 1) {
    int t = (threadIdx.x >= off) ? sh[threadIdx.x - off] : 0;
    __syncthreads();
    sh[threadIdx.x] += t;
    __syncthreads();
  }
  if (i < MLEN) data[(size_t)g * MLEN + i] = sh[threadIdx.x] - x;  // exclusive
  if (threadIdx.x == 255) bsum[g * 512 + blockIdx.x] = sh[255];
}

__global__ __launch_bounds__(512) void scanA2(int* __restrict__ bsum) {
  const int g = blockIdx.x;
  __shared__ int sh[512];
  int x = (threadIdx.x < NBA1) ? bsum[g * 512 + threadIdx.x] : 0;
  sh[threadIdx.x] = x;
  __syncthreads();
  for (int off = 1; off < 512; off <<= 1) {
    int t = (threadIdx.x >= off) ? sh[threadIdx.x - off] : 0;
    __syncthreads();
    sh[threadIdx.x] += t;
    __syncthreads();
  }
  if (threadIdx.x < NBA1) bsum[g * 512 + threadIdx.x] = sh[threadIdx.x] - x;  // exclusive
}

__global__ void scanA3(int* __restrict__ data, const int* __restrict__ bsum) {
  const int g = blockIdx.y;
  int i = blockIdx.x * 256 + threadIdx.x;
  if (i < MLEN) data[(size_t)g * MLEN + i] += bsum[g * 512 + blockIdx.x];
}

// block-local counting sort by coarse bucket + coalesced sequential writeout.
__global__ __launch_bounds__(256) void scatterA(const int* __restrict__ EI, int base,
                                                const int* __restrict__ histM,
                                                unsigned* __restrict__ pack) {
  const int g = blockIdx.y;
  const int* srcp = EI + ((size_t)(base + g) * 2 + 0) * N_EDG;
  const int* dstp = EI + ((size_t)(base + g) * 2 + 1) * N_EDG;
  __shared__ unsigned ed[CHUNK];          // 16 KB: bucket-grouped entries
  __shared__ unsigned short bkt[CHUNK];   // 8 KB: bucket id per slot
  __shared__ int lcnt[NBUCK];
  __shared__ int ebase[NBUCK];
  __shared__ int gbase[NBUCK];
  __shared__ int sc[512];
  const int t = threadIdx.x;
  const int e0 = blockIdx.x * CHUNK;
  const int nE = (N_EDG - e0 < CHUNK) ? (N_EDG - e0) : CHUNK;

  for (int i = t; i < NBUCK; i += 256) {
    lcnt[i] = 0;
    gbase[i] = histM[(size_t)g * MLEN + i * NBLK + blockIdx.x];
  }
  __syncthreads();
  // pass 1: local histogram (reads dst; stays hot in L1/L2 for pass 2)
  for (int k = t; k < nE; k += 256)
    atomicAdd(&lcnt[clampi(dstp[e0 + k]) >> 8], 1);
  __syncthreads();
  // block-wide inclusive scan of 512-padded lcnt (each thread owns 2 slots)
  int v0 = (t < NBUCK) ? lcnt[t] : 0;
  int v1 = (t + 256 < NBUCK) ? lcnt[t + 256] : 0;
  sc[t] = v0; sc[t + 256] = v1;
  __syncthreads();
  for (int off = 1; off < 512; off <<= 1) {
    int a0 = (t >= off) ? sc[t - off] : 0;
    int a1 = (t + 256 >= off) ? sc[t + 256 - off] : 0;
    __syncthreads();
    sc[t] += a0; sc[t + 256] += a1;
    __syncthreads();
  }
  if (t < NBUCK)       { ebase[t] = sc[t] - v0;             lcnt[t] = 0; }
  if (t + 256 < NBUCK) { ebase[t + 256] = sc[t + 256] - v1; lcnt[t + 256] = 0; }
  __syncthreads();
  // pass 2: scatter into LDS, bucket-grouped (rank via LDS atomics)
  for (int k = t; k < nE; k += 256) {
    int d = clampi(dstp[e0 + k]);
    int s = clampi(srcp[e0 + k]);
    int b = d >> 8;
    int slot = ebase[b] + atomicAdd(&lcnt[b], 1);
    ed[slot] = ((unsigned)s << 8) | (unsigned)(d & 255);
    bkt[slot] = (unsigned short)b;
  }
  __syncthreads();
  // pass 3: sequential write-out -> bucket-runs leave as consecutive lanes
  unsigned* pk = pack + (size_t)g * PACK_STRIDE;
  for (int i = t; i < nE; i += 256) {
    int b = bkt[i];
    pk[gbase[b] + (i - ebase[b])] = ed[i];
  }
}

__global__ __launch_bounds__(256) void sortB(const int* __restrict__ histM,
                                             unsigned* __restrict__ pack,
                                             int* __restrict__ rp) {
  const int g = blockIdx.y;
  const int b = blockIdx.x;   // bucket 0..390
  __shared__ unsigned ed[BCAP];
  __shared__ unsigned ed2[BCAP];
  __shared__ int cnt[256];
  __shared__ int sh[256];
  const int t = threadIdx.x;
  const int beg = histM[(size_t)g * MLEN + b * NBLK];
  const int end = (b + 1 < NBUCK) ? histM[(size_t)g * MLEN + (b + 1) * NBLK] : N_EDG;
  int m = end - beg;
  if (m > BCAP) m = BCAP;   // defensive: statistically impossible (78 sigma)
  unsigned* pk = pack + (size_t)g * PACK_STRIDE;

  cnt[t] = 0;
  __syncthreads();
  for (int i = t; i < m; i += 256) {
    unsigned w = pk[beg + i];
    ed[i] = w;
    atomicAdd(&cnt[w & 255u], 1);
  }
  __syncthreads();
  // block-wide Hillis-Steele inclusive scan of cnt -> sh
  int x = cnt[t];
  sh[t] = x;
  __syncthreads();
  for (int off = 1; off < 256; off <<= 1) {
    int tt = (t >= off) ? sh[t - off] : 0;
    __syncthreads();
    sh[t] += tt;
    __syncthreads();
  }
  // rp end-offsets for this bucket's nodes (global edge indexing)
  int n = b * 256 + t;
  if (n < N_NODES) rp[(size_t)g * NBINS + n] = beg + sh[t];
  // cursor = exclusive base
  cnt[t] = sh[t] - x;
  __syncthreads();
  // counting-sort scatter within LDS (order within a node is irrelevant)
  for (int i = t; i < m; i += 256) {
    unsigned w = ed[i];
    int pos = atomicAdd(&cnt[w & 255u], 1);
    ed2[pos] = w >> 8;                    // keep src only
  }
  __syncthreads();
  // in-place, fully coalesced write-back of dst-sorted src list
  for (int i = t; i < m; i += 256) pk[beg + i] = ed2[i];
}

// ---------------- per-node GAT aggregation (16 lanes per node) -------------
// Lane f = tx&15 permanently owns features 4f..4f+3 (no reduction shuffles).
// 4 edges per iteration, SOFTWARE-PIPELINED one iteration ahead: iteration i
// issues iteration i+1's pack load and its dependent H/sS gathers, then
// consumes iteration i's already-resident registers (exp + FMA only).
// Linear node assignment keeps all outputs coalesced (r9 lesson: permuted
// node ids cost more in scattered 64B writes than divergence savings).
// mode 0: X1=bf16(relu(v)); mode 1: online channel combine (O,Mn,Sn).
__global__ __launch_bounds__(256) void aggregate(const unsigned short* __restrict__ H,
                                                 const float* __restrict__ sS,
                                                 const float* __restrict__ sD,
                                                 const int* __restrict__ rp,  // end offsets
                                                 const unsigned* __restrict__ pack,
                                                 const float* __restrict__ bias,
                                                 unsigned short* __restrict__ X1out,
                                                 const float* __restrict__ att_c,
                                                 float* __restrict__ O,
                                                 float* __restrict__ Mn,
                                                 float* __restrict__ Sn,
                                                 float* __restrict__ outF,
                                                 int mode, int first, int last) {
  const int n = blockIdx.x * 16 + (threadIdx.x >> 4);
  const int f = threadIdx.x & 15;       // feature quad: feats 4f..4f+3
  const int beg = (n == 0) ? 0 : rp[n - 1];
  const int end = rp[n];
  const float sDn = sD[n];
  const float wself = __expf(lrelu(sS[n] + sDn));

  // self loop
  uint2 hs = *(const uint2*)(H + ((size_t)n << 6) + (f << 2));
  float a0 = wself * bflo(hs.x);
  float a1 = wself * bfhi(hs.x);
  float a2 = wself * bflo(hs.y);
  float a3 = wself * bfhi(hs.y);
  float den = wself;

  // pipeline registers for the current iteration
  uint2 h[4];
  float ss[4];
  int vm[4];
  int j = beg;
  if (j < end) {
#pragma unroll
    for (int u = 0; u < 4; ++u) {
      unsigned p = pack[j + u];          // padded slot: tail reads safe
      vm[u] = (j + u < end);
      int s = vm[u] ? (int)p : n;
      h[u] = *(const uint2*)(H + ((size_t)s << 6) + (f << 2));
      ss[u] = sS[s];
    }
  }

  for (; j < end; j += 4) {
    const int jn = j + 4;
    uint2 hn[4] = {hs, hs, hs, hs};
    float ssn[4] = {0.f, 0.f, 0.f, 0.f};
    int vn[4] = {0, 0, 0, 0};
    if (jn < end) {  // issue next iteration's loads before consuming current
#pragma unroll
      for (int u = 0; u < 4; ++u) {
        unsigned p = pack[jn + u];
        vn[u] = (jn + u < end);
        int s = vn[u] ? (int)p : n;
        hn[u] = *(const uint2*)(H + ((size_t)s << 6) + (f << 2));
        ssn[u] = sS[s];
      }
    }
    // consume current iteration (registers only)
#pragma unroll
    for (int u = 0; u < 4; ++u) {
      float w = vm[u] ? __expf(lrelu(ss[u] + sDn)) : 0.f;
      den += w;
      a0 += w * bflo(h[u].x);
      a1 += w * bfhi(h[u].x);
      a2 += w * bflo(h[u].y);
      a3 += w * bfhi(h[u].y);
    }
    // rotate pipeline
#pragma unroll
    for (int u = 0; u < 4; ++u) { h[u] = hn[u]; ss[u] = ssn[u]; vm[u] = vn[u]; }
  }

  float v0 = a0 / den + bias[f * 4 + 0];
  float v1 = a1 / den + bias[f * 4 + 1];
  float v2 = a2 / den + bias[f * 4 + 2];
  float v3 = a3 / den + bias[f * 4 + 3];

  if (mode == 0) {
    ushort4 o;
    o.x = f2bf(v0 > 0.f ? v0 : 0.f);
    o.y = f2bf(v1 > 0.f ? v1 : 0.f);
    o.z = f2bf(v2 > 0.f ? v2 : 0.f);
    o.w = f2bf(v3 > 0.f ? v3 : 0.f);
    *(ushort4*)(X1out + (size_t)n * 64 + f * 4) = o;
  } else {
    float sc = v0 * att_c[f * 4 + 0] + v1 * att_c[f * 4 + 1] +
               v2 * att_c[f * 4 + 2] + v3 * att_c[f * 4 + 3];
    sc += __shfl_xor(sc, 1, 16);
    sc += __shfl_xor(sc, 2, 16);
    sc += __shfl_xor(sc, 4, 16);
    sc += __shfl_xor(sc, 8, 16);
    if (first) {
      *(float4*)(O + (size_t)n * 64 + f * 4) = make_float4(v0, v1, v2, v3);
      if (f == 0) { Mn[n] = sc; Sn[n] = 1.f; }
    } else {
      float M = Mn[n];
      float nM = fmaxf(M, sc);
      float scale = __expf(M - nM);
      float wch = __expf(sc - nM);
      float4 o4 = *(const float4*)(O + (size_t)n * 64 + f * 4);
      float o0 = o4.x * scale + wch * v0;
      float o1 = o4.y * scale + wch * v1;
      float o2 = o4.z * scale + wch * v2;
      float o3 = o4.w * scale + wch * v3;
      float s = Sn[n] * scale + wch;
      if (last) {
        *(float4*)(outF + (size_t)n * 64 + f * 4) =
            make_float4(o0 / s, o1 / s, o2 / s, o3 / s);
      } else {
        *(float4*)(O + (size_t)n * 64 + f * 4) = make_float4(o0, o1, o2, o3);
        if (f == 0) { Mn[n] = nM; Sn[n] = s; }
      }
    }
  }
}

// ---------------- host ----------------

extern "C" void kernel_launch(void* const* d_in, const int* in_sizes, int n_in,
                              void* d_out, int out_size, void* d_ws, size_t ws_size,
                              hipStream_t stream) {
  const float* emb = (const float*)d_in[0];
  const float* W1  = (const float*)d_in[1];
  const float* aS1 = (const float*)d_in[2];
  const float* aD1 = (const float*)d_in[3];
  const float* b1  = (const float*)d_in[4];
  const float* W2  = (const float*)d_in[5];
  const float* aS2 = (const float*)d_in[6];
  const float* aD2 = (const float*)d_in[7];
  const float* b2  = (const float*)d_in[8];
  const float* att = (const float*)d_in[9];
  const int*   EI  = (const int*)d_in[10];
  float* out = (float*)d_out;

  const int gElem = (N_NODES * 64) / 256;    // 25000

  // arena ~74 MB; ws_size = 288 MB (r6/r11 fillBuffer evidence: 281250 KB)
  const size_t NEEDED = 75000000;
  if (ws_size < NEEDED) {
    write_const<<<gElem, 256, 0, stream>>>(out, 1000.0f + (float)(ws_size >> 20));
    return;
  }

  float* ws = (float*)d_ws;
  size_t off = 0;
  float* sS = ws + off; off += 100000;
  float* sD = ws + off; off += 100000;
  float* Mn = ws + off; off += 100000;
  float* Sn = ws + off; off += 100000;
  unsigned short* Hbf  = (unsigned short*)(ws + off); off += 3200000;  // bf16 H
  unsigned short* X1bf = (unsigned short*)(ws + off); off += 3200000;  // bf16 x1
  int* histM     = (int*)(ws + off);      off += (size_t)NSLOT * MLEN + 64;
  int* bsumA     = (int*)(ws + off);      off += NSLOT * 512;
  int* rp        = (int*)(ws + off);      off += (size_t)NSLOT * NBINS;
  unsigned* pack = (unsigned*)(ws + off); off += (size_t)NSLOT * PACK_STRIDE;

  const int gGemm = (N_NODES + 127) / 128;   // 782
  const int gRow  = N_NODES / 16;            // 6250
  // O accumulator for the channel combine lives in d_out (write-only until
  // first channel's layer-1 aggregate writes it unconditionally).

  // single build over ALL 18 graphs (slot = gi)
  histA<<<dim3(NBLK, NSLOT), 256, 0, stream>>>(EI, 0, histM);
  scanA1<<<dim3(NBA1, NSLOT), 256, 0, stream>>>(histM, bsumA);
  scanA2<<<NSLOT, 512, 0, stream>>>(bsumA);
  scanA3<<<dim3(NBA1, NSLOT), 256, 0, stream>>>(histM, bsumA);
  scatterA<<<dim3(NBLK, NSLOT), 256, 0, stream>>>(EI, 0, histM, pack);
  sortB<<<dim3(NBUCK, NSLOT), 256, 0, stream>>>(histM, pack, rp);

  for (int c = 0; c < N_CH; ++c) {
    for (int layer = 0; layer < 2; ++layer) {
      const int slot = c * 2 + layer;

      const float* Wf = (layer == 0) ? W1 + (size_t)c * 4096 : W2 + (size_t)c * 4096;
      const float* aS = (layer == 0) ? aS1 + c * 64 : aS2 + c * 64;
      const float* aD = (layer == 0) ? aD1 + c * 64 : aD2 + c * 64;
      const float* bb = (layer == 0) ? b1 + c * 64 : b2 + c * 64;

      if (layer == 0)
        gemm64_f32<<<gGemm, 256, 0, stream>>>(emb, Wf, aS, aD, Hbf, sS, sD, N_NODES);
      else
        gemm64_bf<<<gGemm, 256, 0, stream>>>(X1bf, Wf, aS, aD, Hbf, sS, sD, N_NODES);

      aggregate<<<gRow, 256, 0, stream>>>(Hbf, sS, sD,
                                          rp + (size_t)slot * NBINS,
                                          pack + (size_t)slot * PACK_STRIDE,
                                          bb, X1bf, att + c * 64,
                                          out, Mn, Sn, out,
                                          layer, (c == 0) ? 1 : 0, (c == N_CH - 1) ? 1 : 0);
    }
  }
}